// Round 6
// baseline (362.046 us; speedup 1.0000x reference)
//
#include <hip/hip_runtime.h>
#include <math.h>

// ---------------------------------------------------------------------------
// Segmented softmax: softmax within each contiguous n-best group.
// scores: float32[TOTAL], nBestIndex: int32[NUM_SEG], out: float32[TOTAL].
// Offsets = exclusive prefix sum of nBestIndex (ragged in general).
//
// R7: BARRIER-FREE wave-autonomous pipeline. R6 proved the residual stall is
// the s_waitcnt vmcnt(0) drain the compiler must emit before every s_barrier
// (it drains stage-out STORES, ~us ack latency, every iteration). R7 gives
// each WAVE a private span (16 segments) + private LDS slice: no
// __syncthreads anywhere, so the compiler emits only counted vmcnt for the
// one-span-ahead register prefetch, and stores are never waited on (like the
// 6.5 TB/s fill kernels). Same-wave LDS RAW is in-order in the DS unit.
// Stage-out uses nontemporal stores so the write stream doesn't evict
// scores from the 256MB L3 (keeps FETCH_SIZE low).
// (R7b: nontemporal stores must use a clang native vector type, not HIP's
//  float4 class -- __builtin_nontemporal_store rejects the latter.)
// ---------------------------------------------------------------------------

typedef float f32x4 __attribute__((ext_vector_type(4)));

#define SEGS_W 16                     // segments per wave-span
#define CAPW   1024                   // max stageable span (floats) per wave
#define SBLOCK 256                    // threads per block (4 waves)
#define WPB    4                      // waves per block
#define GRID_C 2048                   // grid cap (256 CU x 8 blocks)

// Kernel A: per-block (256-wide) exclusive scan of counts; block totals out.
__global__ __launch_bounds__(256) void scan_local_kernel(
    const int* __restrict__ counts, int n_seg,
    int* __restrict__ local_scan, int* __restrict__ block_sums) {
    __shared__ int sm[256];
    const int t = threadIdx.x;
    const int g = blockIdx.x * 256 + t;
    const int v = (g < n_seg) ? counts[g] : 0;
    sm[t] = v;
    __syncthreads();
    for (int off = 1; off < 256; off <<= 1) {
        int y = (t >= off) ? sm[t - off] : 0;
        __syncthreads();
        sm[t] += y;
        __syncthreads();
    }
    if (g < n_seg) local_scan[g] = sm[t] - v;   // exclusive within block
    if (t == 255) block_sums[blockIdx.x] = sm[255];
}

// Kernel B: single-block exclusive scan of block_sums in place.
__global__ __launch_bounds__(256) void scan_bsums_kernel(
    int* __restrict__ bsum, int nb) {
    __shared__ int sm[256];
    const int t = threadIdx.x;
    const int per = (nb + 255) >> 8;
    const int beg = t * per;
    const int end = (beg + per < nb) ? beg + per : nb;
    int tot = 0;
    for (int j = beg; j < end; ++j) tot += bsum[j];
    sm[t] = tot;
    __syncthreads();
    for (int off = 1; off < 256; off <<= 1) {
        int y = (t >= off) ? sm[t - off] : 0;
        __syncthreads();
        sm[t] += y;
        __syncthreads();
    }
    int run = sm[t] - tot;
    for (int j = beg; j < end; ++j) {
        int v = bsum[j];
        bsum[j] = run;
        run += v;
    }
}

// Kernel C: barrier-free, wave-autonomous, pipelined segmented softmax.
__global__ __launch_bounds__(SBLOCK) void seg_softmax_kernel(
    const float* __restrict__ scores,
    const int* __restrict__ local_scan, const int* __restrict__ bsum,
    float* __restrict__ out, int n_seg, int total) {

    __shared__ float buf_all[WPB][CAPW];

    const int tid  = threadIdx.x;
    const int wv   = tid >> 6;
    const int lane = tid & 63;
    float* __restrict__ buf = buf_all[wv];

    const int nspans  = (n_seg + SEGS_W - 1) / SEGS_W;
    const int wstride = gridDim.x * WPB;

    int t = blockIdx.x * WPB + wv;
    if (t >= nspans) return;          // wave-uniform, no barriers in kernel

    const int p = lane & 15;          // lane within 16-lane group
    const int g = lane >> 4;          // group 0..3 within wave

    // Absolute element offset of segment s (clamped past the end).
    #define SEG_START(s) (((s) < n_seg) ? (local_scan[(s)] + bsum[(s) >> 8]) : total)

    // ---- prologue: meta(t), meta(t+W); issue data(t) ----
    int tabA = (lane <= SEGS_W) ? SEG_START(t * SEGS_W + lane) : 0;
    int tn   = t + wstride;
    int tabB = (tn < nspans && lane <= SEGS_W) ? SEG_START(tn * SEGS_W + lane) : 0;

    int  b0  = __shfl(tabA, 0);
    int  b1  = __shfl(tabA, SEGS_W);
    bool fit = ((b1 - b0) <= CAPW) && ((b0 & 3) == 0);

    f32x4 r0, r1, r2, r3;
    float rt = 0.0f;
    if (fit) {
        const f32x4* __restrict__ src = (const f32x4*)(scores + b0);
        const int nv = (b1 - b0) >> 2, rm = (b1 - b0) & 3;
        if (lane < nv)        r0 = src[lane];
        if (lane + 64  < nv)  r1 = src[lane + 64];
        if (lane + 128 < nv)  r2 = src[lane + 128];
        if (lane + 192 < nv)  r3 = src[lane + 192];
        if (lane < rm)        rt = scores[b0 + (nv << 2) + lane];
    }

    while (true) {
        const bool haveNext = (tn < nspans);
        const int  span     = b1 - b0;

        // ---- stage-in span t: regs -> wave-private LDS ----
        // (compiler emits counted vmcnt for r*; loads had a full iteration)
        if (fit) {
            const int nv = span >> 2, rm = span & 3;
            f32x4* __restrict__ d = (f32x4*)buf;
            if (lane < nv)        d[lane]       = r0;
            if (lane + 64  < nv)  d[lane + 64]  = r1;
            if (lane + 128 < nv)  d[lane + 128] = r2;
            if (lane + 192 < nv)  d[lane + 192] = r3;
            if (lane < rm)        buf[(nv << 2) + lane] = rt;
        }

        // ---- issue data(t+W) + meta(t+2W): stay in flight over the middle ----
        int  nb0 = 0, nb1 = 0;
        bool fitN = false;
        if (haveNext) {
            nb0  = __shfl(tabB, 0);
            nb1  = __shfl(tabB, SEGS_W);
            fitN = ((nb1 - nb0) <= CAPW) && ((nb0 & 3) == 0);
            if (fitN) {
                const f32x4* __restrict__ src = (const f32x4*)(scores + nb0);
                const int nv2 = (nb1 - nb0) >> 2, rm2 = (nb1 - nb0) & 3;
                if (lane < nv2)        r0 = src[lane];
                if (lane + 64  < nv2)  r1 = src[lane + 64];
                if (lane + 128 < nv2)  r2 = src[lane + 128];
                if (lane + 192 < nv2)  r3 = src[lane + 192];
                if (lane < rm2)        rt = scores[nb0 + (nv2 << 2) + lane];
            }
        }
        const int tnn  = tn + wstride;
        int       tabC = (tnn < nspans && lane <= SEGS_W)
                         ? SEG_START(tnn * SEGS_W + lane) : 0;

        if (fit) {
            // ---- middle: 4 groups x 4 segments, registers + shfl(16) ----
            #pragma unroll
            for (int q = 0; q < 4; ++q) {
                const int ls = g * 4 + q;
                const int sA = __shfl(tabA, ls);
                const int sB = __shfl(tabA, ls + 1);
                const int c  = sB - sA;
                const int s0 = sA - b0;
                if (c <= 0) continue;
                if (c <= 64) {
                    const int i0 = p, i1 = p + 16, i2 = p + 32, i3 = p + 48;
                    float v0 = -INFINITY, v1 = -INFINITY, v2 = -INFINITY, v3 = -INFINITY;
                    if (i0 < c) v0 = buf[s0 + i0];
                    if (i1 < c) v1 = buf[s0 + i1];
                    if (i2 < c) v2 = buf[s0 + i2];
                    if (i3 < c) v3 = buf[s0 + i3];

                    float m = fmaxf(fmaxf(v0, v1), fmaxf(v2, v3));
                    #pragma unroll
                    for (int off = 1; off < 16; off <<= 1)
                        m = fmaxf(m, __shfl_xor(m, off, 16));

                    const float e0 = __expf(v0 - m);   // exp(-INF - m) == 0
                    const float e1 = __expf(v1 - m);
                    const float e2 = __expf(v2 - m);
                    const float e3 = __expf(v3 - m);
                    float s = (e0 + e1) + (e2 + e3);
                    #pragma unroll
                    for (int off = 1; off < 16; off <<= 1)
                        s += __shfl_xor(s, off, 16);

                    const float inv = __builtin_amdgcn_rcpf(s);
                    if (i0 < c) buf[s0 + i0] = e0 * inv;
                    if (i1 < c) buf[s0 + i1] = e1 * inv;
                    if (i2 < c) buf[s0 + i2] = e2 * inv;
                    if (i3 < c) buf[s0 + i3] = e3 * inv;
                } else {
                    // big segment, still LDS-resident: strided 3-pass
                    float m = -INFINITY;
                    for (int j = p; j < c; j += 16)
                        m = fmaxf(m, buf[s0 + j]);
                    #pragma unroll
                    for (int off = 1; off < 16; off <<= 1)
                        m = fmaxf(m, __shfl_xor(m, off, 16));
                    float s = 0.0f;
                    for (int j = p; j < c; j += 16) {
                        const float e = __expf(buf[s0 + j] - m);
                        buf[s0 + j] = e;
                        s += e;
                    }
                    #pragma unroll
                    for (int off = 1; off < 16; off <<= 1)
                        s += __shfl_xor(s, off, 16);
                    const float inv = __builtin_amdgcn_rcpf(s);
                    for (int j = p; j < c; j += 16)
                        buf[s0 + j] *= inv;
                }
            }

            // ---- stage-out: LDS -> global, f32x4 nontemporal ----
            // Same-wave DS ordering guarantees the writes above are visible.
            const int nv = span >> 2, rm = span & 3;
            const f32x4* __restrict__ s4 = (const f32x4*)buf;
            f32x4* __restrict__ dst = (f32x4*)(out + b0);
            for (int k = lane; k < nv; k += 64) {
                const f32x4 vv = s4[k];
                __builtin_nontemporal_store(vv, dst + k);
            }
            if (lane < rm)
                __builtin_nontemporal_store(buf[(nv << 2) + lane],
                                            out + b0 + (nv << 2) + lane);
        } else {
            // ---- slow path: span too big / unaligned -> global 3-pass ----
            #pragma unroll
            for (int q = 0; q < 4; ++q) {
                const int ls = g * 4 + q;
                const int sA = __shfl(tabA, ls);
                const int sB = __shfl(tabA, ls + 1);
                const int c  = sB - sA;
                if (c <= 0) continue;
                float m = -INFINITY;
                for (int j = p; j < c; j += 16)
                    m = fmaxf(m, scores[sA + j]);
                #pragma unroll
                for (int off = 1; off < 16; off <<= 1)
                    m = fmaxf(m, __shfl_xor(m, off, 16));
                float s = 0.0f;
                for (int j = p; j < c; j += 16)
                    s += __expf(scores[sA + j] - m);
                #pragma unroll
                for (int off = 1; off < 16; off <<= 1)
                    s += __shfl_xor(s, off, 16);
                const float inv = __builtin_amdgcn_rcpf(s);
                for (int j = p; j < c; j += 16)
                    out[sA + j] = __expf(scores[sA + j] - m) * inv;
            }
        }

        // ---- rotate pipeline state ----
        if (!haveNext) break;
        t = tn; tn = tnn;
        tabA = tabB; tabB = tabC;
        b0 = nb0; b1 = nb1; fit = fitN;
    }
    #undef SEG_START
}

extern "C" void kernel_launch(void* const* d_in, const int* in_sizes, int n_in,
                              void* d_out, int out_size, void* d_ws, size_t ws_size,
                              hipStream_t stream) {
    const float* scores = (const float*)d_in[0];
    const int*   counts = (const int*)d_in[1];
    float* out = (float*)d_out;
    const int n_seg = in_sizes[1];
    const int total = in_sizes[0];

    // Workspace layout: [n_seg] local exclusive scan | [nblocksA] block sums
    int* local_scan = (int*)d_ws;
    const int nblocksA = (n_seg + 255) / 256;
    int* block_sums = local_scan + n_seg;

    scan_local_kernel<<<nblocksA, 256, 0, stream>>>(counts, n_seg, local_scan, block_sums);
    scan_bsums_kernel<<<1, 256, 0, stream>>>(block_sums, nblocksA);

    const int nspans  = (n_seg + SEGS_W - 1) / SEGS_W;
    const int nblocksC = (nspans + WPB - 1) / WPB;
    const int grid     = (nblocksC < GRID_C) ? nblocksC : GRID_C;
    seg_softmax_kernel<<<grid, SBLOCK, 0, stream>>>(
        scores, local_scan, block_sums, out, n_seg, total);
}

// Round 7
// 347.048 us; speedup vs baseline: 1.0432x; 1.0432x over previous
//
#include <hip/hip_runtime.h>
#include <math.h>

// ---------------------------------------------------------------------------
// Segmented softmax: softmax within each contiguous n-best group.
// scores: float32[TOTAL], nBestIndex: int32[NUM_SEG], out: float32[TOTAL].
// Offsets = exclusive prefix sum of nBestIndex (ragged in general).
//
// R8: DS-PIPE OFFLOAD. R2-R7 (six structures) all plateau at 112-134us with
// VALUBusy 20-30% and HBM ~2.5 TB/s: the shared cost is the per-CU DS pipe
// (shfl_xor = ds_bpermute + scalar b32 LDS middle + staging = ~50-70us/CU
// serialized, invisible in VALUBusy). R8 removes it:
//  - reductions via DPP row_ror (v_mov_dpp: VALU pipe, zero DS); 16-lane
//    groups align exactly with DPP rows.
//  - middle phase reads/writes LDS as per-lane CONTIGUOUS float2 pairs
//    (2x ds_read_b64 + 2x ds_write_b64 per segment vs 8x b32 + 8 bpermute).
//  - float4 block stage-in/out kept from R5 (best measured base).
// ---------------------------------------------------------------------------

#define GSEG   16                          // lanes per segment group (= DPP row)
#define SPG    4                           // segments per group
#define SBLOCK 256                         // threads per softmax block
#define SEGS_B ((SBLOCK / GSEG) * SPG)     // 64 segments per block
#define LDS_FLOATS 3328                    // 13.3 KB span buffer

// ---- DPP 16-lane reductions (VALU pipe; rows of 16 = our groups) ----
template<int CTRL>
__device__ __forceinline__ float dppmov(float x) {
    return __int_as_float(__builtin_amdgcn_update_dpp(
        __float_as_int(x), __float_as_int(x), CTRL, 0xF, 0xF, false));
}
__device__ __forceinline__ float dpp_max16(float m) {
    m = fmaxf(m, dppmov<0x121>(m));   // row_ror:1
    m = fmaxf(m, dppmov<0x122>(m));   // row_ror:2
    m = fmaxf(m, dppmov<0x124>(m));   // row_ror:4
    m = fmaxf(m, dppmov<0x128>(m));   // row_ror:8
    return m;
}
__device__ __forceinline__ float dpp_sum16(float s) {
    s += dppmov<0x121>(s);
    s += dppmov<0x122>(s);
    s += dppmov<0x124>(s);
    s += dppmov<0x128>(s);
    return s;
}

// Kernel A: per-block (256-wide) exclusive scan of counts; block totals out.
__global__ __launch_bounds__(256) void scan_local_kernel(
    const int* __restrict__ counts, int n_seg,
    int* __restrict__ local_scan, int* __restrict__ block_sums) {
    __shared__ int sm[256];
    const int t = threadIdx.x;
    const int g = blockIdx.x * 256 + t;
    const int v = (g < n_seg) ? counts[g] : 0;
    sm[t] = v;
    __syncthreads();
    for (int off = 1; off < 256; off <<= 1) {
        int y = (t >= off) ? sm[t - off] : 0;
        __syncthreads();
        sm[t] += y;
        __syncthreads();
    }
    if (g < n_seg) local_scan[g] = sm[t] - v;   // exclusive within block
    if (t == 255) block_sums[blockIdx.x] = sm[255];
}

// Kernel B: single-block exclusive scan of block_sums in place.
__global__ __launch_bounds__(256) void scan_bsums_kernel(
    int* __restrict__ bsum, int nb) {
    __shared__ int sm[256];
    const int t = threadIdx.x;
    const int per = (nb + 255) >> 8;
    const int beg = t * per;
    const int end = (beg + per < nb) ? beg + per : nb;
    int tot = 0;
    for (int j = beg; j < end; ++j) tot += bsum[j];
    sm[t] = tot;
    __syncthreads();
    for (int off = 1; off < 256; off <<= 1) {
        int y = (t >= off) ? sm[t - off] : 0;
        __syncthreads();
        sm[t] += y;
        __syncthreads();
    }
    int run = sm[t] - tot;
    for (int j = beg; j < end; ++j) {
        int v = bsum[j];
        bsum[j] = run;
        run += v;
    }
}

// Kernel C: float4-streamed, LDS-resident, DPP-reduced segmented softmax.
__global__ __launch_bounds__(SBLOCK) void seg_softmax_kernel(
    const float* __restrict__ scores,
    const int* __restrict__ local_scan, const int* __restrict__ bsum,
    float* __restrict__ out, int n_seg, int total) {
    __shared__ float sm[LDS_FLOATS + 4];        // +4 pad: masked tail reads
    __shared__ int starts[SEGS_B + 1];

    const int tid  = threadIdx.x;
    const int seg0 = blockIdx.x * SEGS_B;

    // Offset table (coalesced; consumed after barrier).
    if (tid <= SEGS_B) {
        const int s = seg0 + tid;
        starts[tid] = (s < n_seg) ? (local_scan[s] + bsum[s >> 8]) : total;
    }

    // Redundant same-address loads broadcast; staging starts pre-barrier.
    const int base = local_scan[seg0] + bsum[seg0 >> 8];
    const int eseg = seg0 + SEGS_B;
    const int bend = (eseg < n_seg) ? (local_scan[eseg] + bsum[eseg >> 8]) : total;
    const int span = bend - base;

    const int p   = tid & (GSEG - 1);           // lane within group (DPP row)
    const int grp = tid >> 4;                   // group 0..15

    if (span <= LDS_FLOATS && (base & 3) == 0) {
        // ---- stage-in: float4, 1KB per wave instruction ----
        const float4* __restrict__ src = (const float4*)(scores + base);
        const int nvec = span >> 2;
        for (int i = tid; i < nvec; i += SBLOCK)
            ((float4*)sm)[i] = src[i];
        for (int i = (nvec << 2) + tid; i < span; i += SBLOCK)
            sm[i] = scores[base + i];
        __syncthreads();

        // ---- middle: per group, 4 segments; contiguous float2 + DPP ----
        #pragma unroll
        for (int q = 0; q < SPG; ++q) {
            const int ls = grp * SPG + q;
            const int s0 = starts[ls] - base;
            const int c  = starts[ls + 1] - starts[ls];
            if (c <= 0) continue;               // group-uniform (row-uniform)

            if (c <= 4 * GSEG && !(s0 & 1)) {
                // lane p owns elements 4p..4p+3 (8B-aligned in LDS)
                const int e0 = 4 * p;
                float2 a = make_float2(-INFINITY, -INFINITY);
                float2 b = make_float2(-INFINITY, -INFINITY);
                const float2* __restrict__ f2 = (const float2*)(sm + s0 + e0);
                if (e0     < c) a = f2[0];      // ds_read_b64
                if (e0 + 2 < c) b = f2[1];
                const float v0 = a.x;
                const float v1 = (e0 + 1 < c) ? a.y : -INFINITY;
                const float v2 = b.x;
                const float v3 = (e0 + 3 < c) ? b.y : -INFINITY;

                float m = fmaxf(fmaxf(v0, v1), fmaxf(v2, v3));
                m = dpp_max16(m);               // VALU-pipe reduction

                const float q0 = __expf(v0 - m);   // exp(-INF - m) == 0
                const float q1 = __expf(v1 - m);
                const float q2 = __expf(v2 - m);
                const float q3 = __expf(v3 - m);
                float s = (q0 + q1) + (q2 + q3);
                s = dpp_sum16(s);

                const float inv = __builtin_amdgcn_rcpf(s);
                float2* __restrict__ o2 = (float2*)(sm + s0 + e0);
                // never write past c (neighbor segment owned by another group)
                if (e0 + 1 < c) {
                    o2[0] = make_float2(q0 * inv, q1 * inv);   // ds_write_b64
                } else if (e0 < c) {
                    sm[s0 + e0] = q0 * inv;
                }
                if (e0 + 3 < c) {
                    o2[1] = make_float2(q2 * inv, q3 * inv);
                } else if (e0 + 2 < c) {
                    sm[s0 + e0 + 2] = q2 * inv;
                }
            } else {
                // general (odd start / big segment): strided b32 + DPP
                float m = -INFINITY;
                for (int j = p; j < c; j += GSEG)
                    m = fmaxf(m, sm[s0 + j]);
                m = dpp_max16(m);
                float s = 0.0f;
                for (int j = p; j < c; j += GSEG) {
                    const float e = __expf(sm[s0 + j] - m);
                    sm[s0 + j] = e;
                    s += e;
                }
                s = dpp_sum16(s);
                const float inv = __builtin_amdgcn_rcpf(s);
                for (int j = p; j < c; j += GSEG)
                    sm[s0 + j] *= inv;
            }
        }
        __syncthreads();

        // ---- stage-out: float4 ----
        float4* __restrict__ dst = (float4*)(out + base);
        for (int i = tid; i < nvec; i += SBLOCK)
            dst[i] = ((const float4*)sm)[i];
        for (int i = (nvec << 2) + tid; i < span; i += SBLOCK)
            out[base + i] = sm[i];
    } else {
        // ---- slow path: span too big / unaligned -> strided global 3-pass ----
        __syncthreads();   // starts[] ready; branch is block-uniform
        #pragma unroll
        for (int q = 0; q < SPG; ++q) {
            const int ls = grp * SPG + q;
            const int st = starts[ls];
            const int c  = starts[ls + 1] - st;
            if (c <= 0) continue;
            float m = -INFINITY;
            for (int j = p; j < c; j += GSEG)
                m = fmaxf(m, scores[st + j]);
            m = dpp_max16(m);
            float s = 0.0f;
            for (int j = p; j < c; j += GSEG)
                s += __expf(scores[st + j] - m);
            s = dpp_sum16(s);
            const float inv = __builtin_amdgcn_rcpf(s);
            for (int j = p; j < c; j += GSEG)
                out[st + j] = __expf(scores[st + j] - m) * inv;
        }
    }
}

extern "C" void kernel_launch(void* const* d_in, const int* in_sizes, int n_in,
                              void* d_out, int out_size, void* d_ws, size_t ws_size,
                              hipStream_t stream) {
    const float* scores = (const float*)d_in[0];
    const int*   counts = (const int*)d_in[1];
    float* out = (float*)d_out;
    const int n_seg = in_sizes[1];
    const int total = in_sizes[0];

    // Workspace layout: [n_seg] local exclusive scan | [nblocksA] block sums
    int* local_scan = (int*)d_ws;
    const int nblocksA = (n_seg + 255) / 256;
    int* block_sums = local_scan + n_seg;

    scan_local_kernel<<<nblocksA, 256, 0, stream>>>(counts, n_seg, local_scan, block_sums);
    scan_bsums_kernel<<<1, 256, 0, stream>>>(block_sums, nblocksA);

    const int nblocksC = (n_seg + SEGS_B - 1) / SEGS_B;
    seg_softmax_kernel<<<nblocksC, SBLOCK, 0, stream>>>(
        scores, local_scan, block_sums, out, n_seg, total);
}